// Round 5
// baseline (341.886 us; speedup 1.0000x reference)
//
#include <hip/hip_runtime.h>
#include <hip/hip_bf16.h>
#include <cstdint>

#define T_SEQ 2048
#define DIM   1024
#define NHEAD 16
#define NKVH  8
#define HDIM  64
#define QKVN  3584   // 2048 (q) + 1024 (k) + 512 (v)

static constexpr float LAMBDA_INIT_F = 0.3555090675909693f;
static constexpr float ONE_MINUS_LI  = 0.6444909324090307f;

typedef __bf16 bf16x8 __attribute__((ext_vector_type(8)));
typedef float  f32x4  __attribute__((ext_vector_type(4)));

static __device__ __forceinline__ ushort f2bf(float f) {
  union { float f; uint32_t u; } x; x.f = f;
  uint32_t u = x.u;
  uint32_t r = (u + 0x7fffu + ((u >> 16) & 1u)) >> 16;
  return (ushort)r;
}
static __device__ __forceinline__ float bf2f(ushort u) {
  union { uint32_t u; float f; } x; x.u = ((uint32_t)u) << 16; return x.f;
}
static __device__ __forceinline__ f32x4 zero4() {
  f32x4 z = {0.f, 0.f, 0.f, 0.f}; return z;
}
// Load one 8-element A/B fragment for mfma_f32_16x16x32_bf16.
// Per-lane k layout: halves at k = 4*(lane>>4) and k = 16 + 4*(lane>>4).
static __device__ __forceinline__ bf16x8 ldfrag(const ushort* p) {
  union { bf16x8 v; uint2 u[2]; } r;
  r.u[0] = *(const uint2*)(p);
  r.u[1] = *(const uint2*)(p + 16);
  return r.v;
}
// async global->LDS, 16B per lane; lds dest = base + lane*16 (wave-uniform base)
static __device__ __forceinline__ void gll16(const ushort* g, ushort* l) {
  __builtin_amdgcn_global_load_lds(
      (const __attribute__((address_space(1))) uint32_t*)g,
      (__attribute__((address_space(3))) uint32_t*)l, 16, 0, 0);
}

// ---------------- fused fp32->bf16 conversion (vectorized x4) ----------------
__global__ void cvt_all(const float* __restrict__ x,  const float* __restrict__ wq,
                        const float* __restrict__ wk, const float* __restrict__ wv,
                        const float* __restrict__ wo,
                        ushort* __restrict__ xb, ushort* __restrict__ Wb,
                        ushort* __restrict__ Wob) {
  int g = (blockIdx.x * 256 + threadIdx.x) * 4;   // < 6815744
  float4 v; ushort* dst;
  if (g < 2097152) {
    v = *(const float4*)(x + g); dst = xb + g;
  } else if (g < 5767168) {
    int j = g - 2097152;
    const float* src = (j < 2097152) ? (wq + j)
                     : (j < 3145728) ? (wk + (j - 2097152))
                                     : (wv + (j - 3145728));
    v = *(const float4*)src; dst = Wb + j;
  } else {
    int j = g - 5767168;
    v = *(const float4*)(wo + j); dst = Wob + j;
  }
  ushort4 o4;
  o4.x = f2bf(v.x); o4.y = f2bf(v.y); o4.z = f2bf(v.z); o4.w = f2bf(v.w);
  *(ushort4*)dst = o4;
}

__global__ void lam_kernel(const float* __restrict__ lq1, const float* __restrict__ lk1,
                           const float* __restrict__ lq2, const float* __restrict__ lk2,
                           float* __restrict__ lam) {
  int lane = threadIdx.x;  // 64 threads
  float p1 = lq1[lane] * lk1[lane];
  float p2 = lq2[lane] * lk2[lane];
  #pragma unroll
  for (int off = 32; off >= 1; off >>= 1) {
    p1 += __shfl_down(p1, off);
    p2 += __shfl_down(p2, off);
  }
  if (lane == 0) *lam = expf(p1) - expf(p2) + LAMBDA_INIT_F;
}

// ---------------- GEMM: C[M][N] = A[M][K] @ W[N][K]^T, m97 structure ----------------
template<int BF16OUT>
__global__ __launch_bounds__(256) void gemm_bt(const ushort* __restrict__ A,
                                               const ushort* __restrict__ W,
                                               void* __restrict__ Cout,
                                               int M, int N, int K) {
  __shared__ ushort As[128 * 32];
  __shared__ ushort Ws[128 * 32];
  const int tid  = threadIdx.x;
  const int lane = tid & 63;
  const int w    = tid >> 6;
  const int wr   = w >> 1, wc = w & 1;
  const int bm   = blockIdx.y * 128, bn = blockIdx.x * 128;
  const int fr   = lane & 15;
  const int fg   = (lane >> 4) * 4;

  f32x4 acc[4][4];
  #pragma unroll
  for (int m = 0; m < 4; ++m)
    #pragma unroll
    for (int n = 0; n < 4; ++n) acc[m][n] = zero4();

  const int col  = (lane & 3) * 8;
  const int row0 = w * 16 + (lane >> 2);
  const int row1 = row0 + 64;
  const ushort* ga0 = A + (size_t)(bm + row0) * K + col;
  const ushort* ga1 = A + (size_t)(bm + row1) * K + col;
  const ushort* gw0 = W + (size_t)(bn + row0) * K + col;
  const ushort* gw1 = W + (size_t)(bn + row1) * K + col;
  ushort* la0 = As + (w * 512);
  ushort* la1 = As + (w * 512) + 2048;
  ushort* lw0 = Ws + (w * 512);
  ushort* lw1 = Ws + (w * 512) + 2048;

  for (int k0 = 0; k0 < K; k0 += 32) {
    gll16(ga0 + k0, la0);
    gll16(ga1 + k0, la1);
    gll16(gw0 + k0, lw0);
    gll16(gw1 + k0, lw1);
    __syncthreads();
    bf16x8 af[4], bfr[4];
    #pragma unroll
    for (int m = 0; m < 4; ++m) af[m]  = ldfrag(&As[(wr*64 + m*16 + fr) * 32 + fg]);
    #pragma unroll
    for (int n = 0; n < 4; ++n) bfr[n] = ldfrag(&Ws[(wc*64 + n*16 + fr) * 32 + fg]);
    #pragma unroll
    for (int m = 0; m < 4; ++m)
      #pragma unroll
      for (int n = 0; n < 4; ++n)
        acc[m][n] = __builtin_amdgcn_mfma_f32_16x16x32_bf16(af[m], bfr[n], acc[m][n], 0, 0, 0);
    __syncthreads();
  }

  #pragma unroll
  for (int m = 0; m < 4; ++m)
    #pragma unroll
    for (int n = 0; n < 4; ++n)
      #pragma unroll
      for (int i = 0; i < 4; ++i) {
        int row = bm + wr*64 + m*16 + fg + i;
        int colg = bn + wc*64 + n*16 + fr;
        float v = acc[m][n][i];
        if (BF16OUT) ((ushort*)Cout)[(size_t)row * N + colg] = f2bf(v);
        else         ((float*)Cout)[(size_t)row * N + colg]  = v;
      }
}

// ---------------- fused RoPE Q, RoPE K, pack V (vectorized) ----------------
__global__ void reorg(const ushort* __restrict__ QKV, ushort* __restrict__ Qr,
                      ushort* __restrict__ Kr, ushort* __restrict__ Vt,
                      const float* __restrict__ fc, const float* __restrict__ fs) {
  int idx = blockIdx.x * 256 + threadIdx.x;   // < 917504
  if (idx < 786432) {
    // RoPE, 4 interleaved pairs (8 bf16) per thread
    int nheads, col_off; ushort* dst; float scale; int id;
    if (idx < 524288) { id = idx * 4; nheads = NHEAD; col_off = 0; dst = Qr; scale = 0.125f; }
    else { id = (idx - 524288) * 4; nheads = NKVH; col_off = 2048; dst = Kr; scale = 1.0f; }
    int per_t = nheads * 64;
    int t  = id / per_t;
    int r  = id - t * per_t;
    int hh = r >> 6;
    int c2 = (r >> 5) & 1;
    int j  = r & 31;                      // multiple of 4
    int cl = col_off + hh * 128 + c2 * 64 + 2 * j;
    uint4 raw = *(const uint4*)(QKV + (size_t)t * QKVN + cl);
    const ushort* rp = (const ushort*)&raw;
    float c4[4], s4[4];
    *(float4*)c4 = *(const float4*)(fc + t * 32 + j);
    *(float4*)s4 = *(const float4*)(fs + t * 32 + j);
    ushort outv[8];
    #pragma unroll
    for (int p = 0; p < 4; ++p) {
      float rv = bf2f(rp[2*p]), iv = bf2f(rp[2*p + 1]);
      outv[2*p]     = f2bf((rv * c4[p] - iv * s4[p]) * scale);
      outv[2*p + 1] = f2bf((rv * s4[p] + iv * c4[p]) * scale);
    }
    size_t o = ((size_t)(c2 * nheads + hh) * T_SEQ + t) * HDIM + 2 * j;
    *(uint4*)(dst + o) = *(const uint4*)outv;
  } else {
    // V transpose: 8 t-consecutive elems -> one contiguous store
    int id = (idx - 786432) * 8;           // < 1048576
    int t = id & (T_SEQ - 1);              // multiple of 8
    int rest = id >> 11;                   // kh*64 + d
    ushort outv[8];
    #pragma unroll
    for (int p = 0; p < 8; ++p) outv[p] = QKV[(size_t)(t + p) * QKVN + 3072 + rest];
    *(uint4*)(Vt + (size_t)rest * T_SEQ + t) = *(const uint4*)outv;
  }
}

// ---------------- flash attention, fused differential combine + LN partials -------
// Block = (head h, 64-row q-block qb). 4 waves = (stream st, q-half hf), 32 q each.
// K1/K2/V staged once per block in double-buffered LDS; ONE barrier per tile.
// Epilogue: stream-1 waves park O2/l2 in LDS; stream-0 waves write Y = O1/l1 - lam*O2/l2
// and reduce per-block sum/sumsq partials.
__global__ __launch_bounds__(256, 3) void attn_kernel(const ushort* __restrict__ Qr,
                                                      const ushort* __restrict__ Kr,
                                                      const ushort* __restrict__ Vt,
                                                      const float* __restrict__ lamp,
                                                      float* __restrict__ Yf,
                                                      float* __restrict__ part) {
  const int bx = blockIdx.x;            // 0..511, heaviest qb first
  const int h  = bx & 15;
  const int qb = 31 - (bx >> 4);
  const int kh = h >> 1;
  const int tid = threadIdx.x;
  const int lane = tid & 63;
  const int w  = tid >> 6;
  const int st = w >> 1;                // stream 0/1
  const int hf = w & 1;                 // q-half 0/1
  const int fr = lane & 15;
  const int fg = (lane >> 4) * 4;

  __shared__ ushort S[2][3][64][70];    // [buf][K1,K2,V][row][col(pad 70)]
  __shared__ float sb[4];

  const int qrow0 = qb * 64 + hf * 32;

  // Q fragments (pre-scaled 1/8), B-operand (col = q)
  bf16x8 qf[2][2];
  #pragma unroll
  for (int qs = 0; qs < 2; ++qs) {
    const ushort* qp = Qr + ((size_t)(st * NHEAD + h) * T_SEQ + qrow0 + qs * 16 + fr) * HDIM;
    qf[qs][0] = ldfrag(qp + fg);
    qf[qs][1] = ldfrag(qp + 32 + fg);
  }

  float m_[2] = {-__builtin_inff(), -__builtin_inff()};
  float l_[2] = {0.f, 0.f};
  f32x4 o_[2][4];
  #pragma unroll
  for (int qs = 0; qs < 2; ++qs)
    #pragma unroll
    for (int dn = 0; dn < 4; ++dn) o_[qs][dn] = zero4();

  // staging: thread t covers row = t>>2, 32 cols at (t&3)*16 for each of K1,K2,V
  const int srow = tid >> 2, scol = (tid & 3) * 16;
  const ushort* k1g = Kr + ((size_t)kh * T_SEQ + srow) * HDIM + scol;
  const ushort* k2g = Kr + ((size_t)(NKVH + kh) * T_SEQ + srow) * HDIM + scol;
  const ushort* vg  = Vt + (size_t)(kh * 64 + srow) * T_SEQ + scol;

  uint4 pre0, pre1, pre2, pre3, pre4, pre5;
  {
    pre0 = *(const uint4*)k1g;       pre1 = *(const uint4*)(k1g + 8);
    pre2 = *(const uint4*)k2g;       pre3 = *(const uint4*)(k2g + 8);
    pre4 = *(const uint4*)vg;        pre5 = *(const uint4*)(vg + 8);
  }
  // prologue store to buf 0
  *(uint4*)&S[0][0][srow][scol]     = pre0;
  *(uint4*)&S[0][0][srow][scol + 8] = pre1;
  *(uint4*)&S[0][1][srow][scol]     = pre2;
  *(uint4*)&S[0][1][srow][scol + 8] = pre3;
  *(uint4*)&S[0][2][srow][scol]     = pre4;
  *(uint4*)&S[0][2][srow][scol + 8] = pre5;

  int cur = 0;
  for (int kt = 0; kt <= qb; ++kt) {
    __syncthreads();                  // buf[cur] staged; prior reads of buf[cur^1] done
    if (kt < qb) {                    // issue next tile's loads early (T14)
      const ushort* a = k1g + (size_t)(kt + 1) * 64 * HDIM;
      const ushort* b = k2g + (size_t)(kt + 1) * 64 * HDIM;
      const ushort* c = vg  + (size_t)(kt + 1) * 64;
      pre0 = *(const uint4*)a; pre1 = *(const uint4*)(a + 8);
      pre2 = *(const uint4*)b; pre3 = *(const uint4*)(b + 8);
      pre4 = *(const uint4*)c; pre5 = *(const uint4*)(c + 8);
    }

    // S^T = mfma(K rows, Q cols): lane holds q=fr, keys n*16+fg+i
    float sv[2][4][4];
    #pragma unroll
    for (int n = 0; n < 4; ++n) {
      bf16x8 ak0 = ldfrag(&S[cur][st][n*16 + fr][fg]);
      bf16x8 ak1 = ldfrag(&S[cur][st][n*16 + fr][32 + fg]);
      #pragma unroll
      for (int qs = 0; qs < 2; ++qs) {
        f32x4 acc = zero4();
        acc = __builtin_amdgcn_mfma_f32_16x16x32_bf16(ak0, qf[qs][0], acc, 0, 0, 0);
        acc = __builtin_amdgcn_mfma_f32_16x16x32_bf16(ak1, qf[qs][1], acc, 0, 0, 0);
        #pragma unroll
        for (int i = 0; i < 4; ++i) sv[qs][n][i] = acc[i];
      }
    }
    if (kt == qb) {                   // causal mask on diagonal tile
      #pragma unroll
      for (int qs = 0; qs < 2; ++qs) {
        const int qloc = hf*32 + qs*16 + fr;
        #pragma unroll
        for (int n = 0; n < 4; ++n)
          #pragma unroll
          for (int i = 0; i < 4; ++i)
            if (n*16 + fg + i > qloc) sv[qs][n][i] = -__builtin_inff();
      }
    }

    bf16x8 pa[2][2];
    #pragma unroll
    for (int qs = 0; qs < 2; ++qs) {
      float rm = -__builtin_inff();
      #pragma unroll
      for (int n = 0; n < 4; ++n)
        #pragma unroll
        for (int i = 0; i < 4; ++i) rm = fmaxf(rm, sv[qs][n][i]);
      rm = fmaxf(rm, __shfl_xor(rm, 16));
      rm = fmaxf(rm, __shfl_xor(rm, 32));
      float mnew = fmaxf(m_[qs], rm);
      float sc = __expf(m_[qs] - mnew);
      m_[qs] = mnew;
      float rs = 0.f;
      #pragma unroll
      for (int n = 0; n < 4; ++n)
        #pragma unroll
        for (int i = 0; i < 4; ++i) {
          float p = __expf(sv[qs][n][i] - mnew);
          sv[qs][n][i] = p; rs += p;
        }
      rs += __shfl_xor(rs, 16);
      rs += __shfl_xor(rs, 32);
      l_[qs] = l_[qs] * sc + rs;
      float scs[4];
      #pragma unroll
      for (int i = 0; i < 4; ++i) scs[i] = __shfl(sc, fg + i);
      #pragma unroll
      for (int dn = 0; dn < 4; ++dn)
        #pragma unroll
        for (int i = 0; i < 4; ++i) o_[qs][dn][i] *= scs[i];
      #pragma unroll
      for (int ks = 0; ks < 2; ++ks)
        #pragma unroll
        for (int n2 = 0; n2 < 2; ++n2)
          #pragma unroll
          for (int i = 0; i < 4; ++i)
            pa[qs][ks][n2*4 + i] = (__bf16)sv[qs][2*ks + n2][i];
    }

    // O += P @ V (V shared by both streams/halves)
    #pragma unroll
    for (int ks = 0; ks < 2; ++ks)
      #pragma unroll
      for (int dn = 0; dn < 4; ++dn) {
        bf16x8 bv = ldfrag(&S[cur][2][dn*16 + fr][ks*32 + fg]);
        o_[0][dn] = __builtin_amdgcn_mfma_f32_16x16x32_bf16(pa[0][ks], bv, o_[0][dn], 0, 0, 0);
        o_[1][dn] = __builtin_amdgcn_mfma_f32_16x16x32_bf16(pa[1][ks], bv, o_[1][dn], 0, 0, 0);
      }

    if (kt < qb) {                    // late LDS write of prefetched tile
      int nb = cur ^ 1;
      *(uint4*)&S[nb][0][srow][scol]     = pre0;
      *(uint4*)&S[nb][0][srow][scol + 8] = pre1;
      *(uint4*)&S[nb][1][srow][scol]     = pre2;
      *(uint4*)&S[nb][1][srow][scol + 8] = pre3;
      *(uint4*)&S[nb][2][srow][scol]     = pre4;
      *(uint4*)&S[nb][2][srow][scol + 8] = pre5;
    }
    cur ^= 1;
  }

  // epilogue: combine streams in LDS
  float li[2][4];
  #pragma unroll
  for (int qs = 0; qs < 2; ++qs)
    #pragma unroll
    for (int i = 0; i < 4; ++i) li[qs][i] = __shfl(l_[qs], fg + i);

  float* ob = (float*)&S[0][0][0][0];   // 16 KB scratch over dead K/V buffers
  __syncthreads();                       // all LDS reads of the loop complete
  if (st == 1) {
    #pragma unroll
    for (int qs = 0; qs < 2; ++qs)
      #pragma unroll
      for (int dn = 0; dn < 4; ++dn)
        #pragma unroll
        for (int i = 0; i < 4; ++i)
          ob[hf*2048 + (qs*16 + fg + i)*64 + dn*16 + fr] = o_[qs][dn][i] / li[qs][i];
  }
  __syncthreads();
  if (st == 0) {
    const float lam = *lamp;
    float s = 0.f, s2 = 0.f;
    #pragma unroll
    for (int qs = 0; qs < 2; ++qs)
      #pragma unroll
      for (int dn = 0; dn < 4; ++dn)
        #pragma unroll
        for (int i = 0; i < 4; ++i) {
          int ql = qs*16 + fg + i, d = dn*16 + fr;
          float v = o_[qs][dn][i] / li[qs][i] - lam * ob[hf*2048 + ql*64 + d];
          Yf[(size_t)(qrow0 + ql) * DIM + h*64 + d] = v;
          s += v; s2 += v * v;
        }
    #pragma unroll
    for (int off = 1; off <= 32; off <<= 1) {
      s  += __shfl_xor(s, off);
      s2 += __shfl_xor(s2, off);
    }
    if (lane == 0) { sb[hf] = s; sb[2 + hf] = s2; }
  }
  __syncthreads();
  if (tid == 0) {
    part[bx]       = sb[0] + sb[1];
    part[512 + bx] = sb[2] + sb[3];
  }
}

// ---------------- finalize per-head stats ----------------
__global__ void stats_final(const float* __restrict__ part, float* __restrict__ stat) {
  int hh = threadIdx.x;
  if (hh < 16) {
    float S = 0.f, S2 = 0.f;
    #pragma unroll
    for (int j = 0; j < 32; ++j) { S += part[j*16 + hh]; S2 += part[512 + j*16 + hh]; }
    const float N = (float)(T_SEQ * HDIM);
    float mean = S / N;
    float var  = S2 / N - mean * mean;
    stat[hh]      = mean;
    stat[16 + hh] = rsqrtf(var + 1e-5f);
  }
}

__global__ void norm_cvt(const float* __restrict__ Y, const float* __restrict__ stats,
                         ushort* __restrict__ Yb) {
  int idx = blockIdx.x * 256 + threadIdx.x;
  int col = idx & (DIM - 1);
  int h = col >> 6;
  float v = (Y[idx] - stats[h]) * stats[16 + h] * ONE_MINUS_LI;
  Yb[idx] = f2bf(v);
}

// ---------------- launch ----------------
extern "C" void kernel_launch(void* const* d_in, const int* in_sizes, int n_in,
                              void* d_out, int out_size, void* d_ws, size_t ws_size,
                              hipStream_t stream) {
  const float* x   = (const float*)d_in[0];
  const float* fc  = (const float*)d_in[1];
  const float* fs  = (const float*)d_in[2];
  const float* wq  = (const float*)d_in[3];
  const float* wk  = (const float*)d_in[4];
  const float* wv  = (const float*)d_in[5];
  const float* wo  = (const float*)d_in[6];
  const float* lq1 = (const float*)d_in[7];
  const float* lk1 = (const float*)d_in[8];
  const float* lq2 = (const float*)d_in[9];
  const float* lk2 = (const float*)d_in[10];
  float* out = (float*)d_out;

  char* ws = (char*)d_ws;
  const size_t OFF_WOB  = 0;                 // 2 MB, live till end
  const size_t OFF_XB   = 2097152;           // 4 MB, dead after gemm1
  const size_t OFF_WB   = 6291456;           // 7 MB, dead after gemm1
  const size_t OFF_QKV  = 13631488;          // 14.68 MB, dead after reorg
  const size_t OFF_QR   = 28311552;          // 8 MB
  const size_t OFF_KR   = 36700160;          // 4 MB
  const size_t OFF_VT   = 40894464;          // 2 MB
  const size_t OFF_Y    = 18874368;          // 8 MB over dead QKV tail
  const size_t OFF_YB   = 42991616;          // 4 MB
  const size_t OFF_ST   = 47185920;          // stats + lam + partials

  ushort* xb   = (ushort*)(ws + OFF_XB);
  ushort* Wb   = (ushort*)(ws + OFF_WB);
  ushort* Wob  = (ushort*)(ws + OFF_WOB);
  ushort* QKVb = (ushort*)(ws + OFF_QKV);
  ushort* Qr   = (ushort*)(ws + OFF_QR);
  ushort* Kr   = (ushort*)(ws + OFF_KR);
  ushort* Vt   = (ushort*)(ws + OFF_VT);
  float*  Yf   = (float*)(ws + OFF_Y);
  ushort* Yb   = (ushort*)(ws + OFF_YB);
  float*  stat = (float*)(ws + OFF_ST);
  float*  lamp = stat + 32;
  float*  part = stat + 64;                  // 1024 floats

  cvt_all<<<6656, 256, 0, stream>>>(x, wq, wk, wv, wo, xb, Wb, Wob);
  lam_kernel<<<1, 64, 0, stream>>>(lq1, lk1, lq2, lk2, lamp);

  gemm_bt<1><<<dim3(QKVN/128, T_SEQ/128), 256, 0, stream>>>(xb, Wb, QKVb, T_SEQ, QKVN, DIM);

  reorg<<<3584, 256, 0, stream>>>(QKVb, Qr, Kr, Vt, fc, fs);

  attn_kernel<<<512, 256, 0, stream>>>(Qr, Kr, Vt, lamp, Yf, part);

  stats_final<<<1, 64, 0, stream>>>(part, stat);
  norm_cvt<<<8192, 256, 0, stream>>>(Yf, stat, Yb);

  gemm_bt<0><<<dim3(DIM/128, T_SEQ/128), 256, 0, stream>>>(Yb, Wob, out, T_SEQ, DIM, DIM);
}